// Round 3
// baseline (541.535 us; speedup 1.0000x reference)
//
#include <hip/hip_runtime.h>

// Problem dims (fixed by setup_inputs): B=1, C=32, H=W=1024, fp32.
constexpr int C  = 32;
constexpr int H  = 1024;
constexpr int W  = 1024;
constexpr int HW = H * W;

// ---------------------------------------------------------------------------
// Single-pass fused STN gather, native [C][H][W] layout (no transpose pass,
// no workspace).
//
// Per pixel, per channel, per row r∈{y0,y1}: the two x-corners are adjacent
// floats -> ONE dwordx2 covers both. Clamp/OOB cases fold into per-element
// weights computed once in phase A:
//   cb  = clamp(x0, 0, W-2)              (float2 window [cb, cb+1])
//   eA_r = wA*[xc0==cb]   + wB*[xc1==cb]     (wA,wB) = (w00,w10) row0,
//   eB_r = wA*[xc0==cb+1] + wB*[xc1==cb+1]             (w01,w11) row1
// Interior: eA0=w00 eB0=w10 eA1=w01 eB1=w11 -> identical FMA association to
// the previously-passing kernel:  r0 = v00*w00 + v10*w10; r1 = v01*w01 +
// v11*w11; out = r0 + r1.
//
// vmem budget: gather 1.0 instr/px (8 lanes/px x 8 dwordx2) + stores 0.125
// (LDS-staged channel transpose, 512B segments) + flow 0.03  ~= 1.16/px.
// ---------------------------------------------------------------------------
constexpr int GP_PX   = 64;          // pixels per 256-thread block
constexpr int RES_PAD = GP_PX + 5;   // 69: channel stride 5 mod 32 -> <=2-way banks

__global__ __launch_bounds__(256) void stn_fused(
    const float* __restrict__ flow,
    const float* __restrict__ x,
    float* __restrict__ out)
{
    __shared__ float prm[GP_PX][8];    // eA0,eB0,eA1,eB1, addr0, addr1, -, -
    __shared__ float res[C][RES_PAD];  // staged output, px-major per channel (~8.8 KB)

    // Bijective chunked XCD swizzle (nwg = 16384, divisible by 8): each XCD
    // gets a contiguous 128-row band -> x-row reuse stays in one L2/L3 slice.
    const int nwg = gridDim.x;
    const int nb  = (blockIdx.x & 7) * (nwg >> 3) + (blockIdx.x >> 3);
    const int pxbase = nb * GP_PX;
    const int t = threadIdx.x;

    // ---- Phase A: per-pixel weights + row base addresses (coalesced flow) --
    if (t < GP_PX) {
        const int p  = pxbase + t;
        const int w_ = p & (W - 1);
        const int h_ = p >> 10;

        const float fx = flow[p];
        const float fy = flow[HW + p];

        // Mirror reference arithmetic order exactly (fp32).
        const float gx = (fx + (float)w_) / (float)(W - 1) * 2.0f - 1.0f;
        const float gy = (fy + (float)h_) / (float)(H - 1) * 2.0f - 1.0f;
        const float ix = ((gx + 1.0f) * (float)W - 1.0f) * 0.5f;
        const float iy = ((gy + 1.0f) * (float)H - 1.0f) * 0.5f;

        const float x0f = floorf(ix);
        const float y0f = floorf(iy);
        const float wx1 = ix - x0f;
        const float wy1 = iy - y0f;
        const float wx0 = 1.0f - wx1;
        const float wy0 = 1.0f - wy1;

        const int x0 = (int)x0f;
        const int y0 = (int)y0f;
        const int x1 = x0 + 1;
        const int y1 = y0 + 1;

        const float vx0 = (x0 >= 0 && x0 < W) ? 1.0f : 0.0f;
        const float vx1 = (x1 >= 0 && x1 < W) ? 1.0f : 0.0f;
        const float vy0 = (y0 >= 0 && y0 < H) ? 1.0f : 0.0f;
        const float vy1 = (y1 >= 0 && y1 < H) ? 1.0f : 0.0f;

        const float w00 = wx0 * wy0 * vx0 * vy0;
        const float w10 = wx1 * wy0 * vx1 * vy0;
        const float w01 = wx0 * wy1 * vx0 * vy1;
        const float w11 = wx1 * wy1 * vx1 * vy1;

        const int xc0 = min(max(x0, 0), W - 1);
        const int xc1 = min(max(x1, 0), W - 1);
        const int yc0 = min(max(y0, 0), H - 1);
        const int yc1 = min(max(y1, 0), H - 1);

        const int cb = min(max(x0, 0), W - 2);   // float2 window [cb, cb+1]

        // Fold column-clamp into element weights (interior: eA0=w00 eB0=w10 ...).
        const float eA0 = ((xc0 == cb)     ? w00 : 0.0f) + ((xc1 == cb)     ? w10 : 0.0f);
        const float eB0 = ((xc0 == cb + 1) ? w00 : 0.0f) + ((xc1 == cb + 1) ? w10 : 0.0f);
        const float eA1 = ((xc0 == cb)     ? w01 : 0.0f) + ((xc1 == cb)     ? w11 : 0.0f);
        const float eB1 = ((xc0 == cb + 1) ? w01 : 0.0f) + ((xc1 == cb + 1) ? w11 : 0.0f);

        // Two b128 LDS writes (avoid 16-way scalar-write conflicts).
        *(float4*)&prm[t][0] = make_float4(eA0, eB0, eA1, eB1);
        *(float4*)&prm[t][4] = make_float4(__int_as_float(yc0 * W + cb),
                                           __int_as_float(yc1 * W + cb),
                                           0.0f, 0.0f);
    }
    __syncthreads();

    // ---- Phase B: gather. 8 lanes/px, lane j owns channels 4j..4j+3.
    // 2 px per thread -> 16 dwordx2 loads batched in flight. ---------------
    const int j  = t & 7;      // channel quad
    const int ps = t >> 3;     // pixel slot 0..31 (block-wide)

    float4 wq[2];
    int    a0[2], a1[2];
#pragma unroll
    for (int q = 0; q < 2; ++q) {
        const int px = q * 32 + ps;
        wq[q] = *(const float4*)&prm[px][0];              // broadcast reads
        const float2 ab = *(const float2*)&prm[px][4];
        a0[q] = __float_as_int(ab.x);
        a1[q] = __float_as_int(ab.y);
    }

    const float* __restrict__ xb = x + (size_t)j * 4 * HW;  // lane channel base

    float2 v[2][8];   // [q][i*2 + r]: channel i = 4j+i, row r
#pragma unroll
    for (int q = 0; q < 2; ++q) {
#pragma unroll
        for (int i = 0; i < 4; ++i) {
            v[q][2 * i + 0] = *(const float2*)(xb + (size_t)i * HW + a0[q]);
            v[q][2 * i + 1] = *(const float2*)(xb + (size_t)i * HW + a1[q]);
        }
    }
    __builtin_amdgcn_sched_barrier(0);   // keep all 16 loads batched

    // ---- Phase C: interpolate + stage to LDS (px-major per channel) -------
#pragma unroll
    for (int q = 0; q < 2; ++q) {
        const int px = q * 32 + ps;
#pragma unroll
        for (int i = 0; i < 4; ++i) {
            const float r0 = v[q][2 * i + 0].x * wq[q].x + v[q][2 * i + 0].y * wq[q].y;
            const float r1 = v[q][2 * i + 1].x * wq[q].z + v[q][2 * i + 1].y * wq[q].w;
            res[4 * j + i][px] = r0 + r1;
        }
    }
    __syncthreads();

    // ---- Phase D: coalesced float4 stores over channel planes -------------
    // 512 float4 per block = 2 per thread; per-wave 4 x 256 B segments.
    float4* __restrict__ out4 = (float4*)out;
    const int gbase = pxbase >> 2;
#pragma unroll
    for (int m = 0; m < 2; ++m) {
        const int f = m * 256 + t;
        const int c = f >> 4;          // channel
        const int g = f & 15;          // float4 group within 64-px tile
        float4 o;
        o.x = res[c][4 * g + 0];
        o.y = res[c][4 * g + 1];
        o.z = res[c][4 * g + 2];
        o.w = res[c][4 * g + 3];
        out4[(size_t)c * (HW / 4) + gbase + g] = o;
    }
}

extern "C" void kernel_launch(void* const* d_in, const int* in_sizes, int n_in,
                              void* d_out, int out_size, void* d_ws, size_t ws_size,
                              hipStream_t stream) {
    const float* flow = (const float*)d_in[0];  // [1,2,1024,1024]
    const float* x    = (const float*)d_in[1];  // [1,32,1024,1024]
    float* out        = (float*)d_out;          // [1,32,1024,1024]

    (void)d_ws; (void)ws_size;                  // no workspace needed anymore
    stn_fused<<<HW / GP_PX, 256, 0, stream>>>(flow, x, out);
}

// Round 5
// 289.520 us; speedup vs baseline: 1.8705x; 1.8705x over previous
//
#include <hip/hip_runtime.h>

// Problem dims (fixed by setup_inputs): B=1, C=32, H=W=1024, fp32.
constexpr int C  = 32;
constexpr int H  = 1024;
constexpr int W  = 1024;
constexpr int HW = H * W;

// Native clang vector type: __builtin_nontemporal_* requires scalar/ext-vector
// pointee (HIP_vector_type float4 is rejected).
typedef float vf4 __attribute__((ext_vector_type(4)));

// ---------------------------------------------------------------------------
// Pass 1 v2: transpose x [C,H,W] -> xp [H*W][C] (pixel-major, 128 B records).
// 512 px per block, 512 threads: each channel read as a 2 KB contiguous run
// (vs 1 KB before) to improve DRAM stream efficiency; nontemporal x loads so
// L3 keeps xp (which the gather re-reads) instead of dead x lines.
// ---------------------------------------------------------------------------
constexpr int TP_PX = 512;
constexpr int TPAD  = 516;   // floats per channel row in LDS (16B-aligned rows)

__global__ __launch_bounds__(512) void transpose_v2(
    const float* __restrict__ x, float* __restrict__ xp)
{
    __shared__ float lds[C * TPAD];   // 66.0 KB -> 2 blocks/CU, 16 waves/CU
    const int p0 = blockIdx.x * TP_PX;
    const int t  = threadIdx.x;
    const int pl = t & 63;     // float4 slot within a 256-px half-tile
    const int cg = t >> 6;     // wave id 0..7 -> channel subgroup

    const vf4* __restrict__ x4 = (const vf4*)x;

    // 8 batched loads/thread; instr pairs (half=0,1) cover 2 KB contiguous
    // per channel.
    vf4 v[8];
#pragma unroll
    for (int i = 0; i < 8; ++i) {
        const int c    = (i >> 1) * 8 + cg;
        const int half = i & 1;
        v[i] = __builtin_nontemporal_load(
            &x4[(size_t)c * (HW / 4) + (p0 >> 2) + half * 64 + pl]);
    }
    __builtin_amdgcn_sched_barrier(0);   // keep loads hoisted/batched

#pragma unroll
    for (int i = 0; i < 8; ++i) {
        const int c    = (i >> 1) * 8 + cg;
        const int half = i & 1;
        *(vf4*)&lds[c * TPAD + (half * 64 + pl) * 4] = v[i];
    }
    __syncthreads();

    // Store: flat float4 index f over the block's 4096-float4 output region;
    // consecutive lanes -> consecutive float4s (coalesced 1 KB/instr).
    vf4* __restrict__ xp4 = (vf4*)xp + (size_t)p0 * 8;
#pragma unroll
    for (int m = 0; m < 8; ++m) {
        const int f  = m * 512 + t;
        const int px = f >> 3;        // pixel within tile (0..511)
        const int j  = f & 7;         // float4 within record (channels 4j..4j+3)
        vf4 o;
        o.x = lds[(j * 4 + 0) * TPAD + px];
        o.y = lds[(j * 4 + 1) * TPAD + px];
        o.z = lds[(j * 4 + 2) * TPAD + px];
        o.w = lds[(j * 4 + 3) * TPAD + px];
        xp4[f] = o;
    }
}

// ---------------------------------------------------------------------------
// Pass 2 (R2 gather_v3, proven 88 us): minimize vmem wave-instructions.
//   gather: 0.5 instr/px (floor: 512 B corner data, 16 B/lane, full-line
//           utilization via pixel-major records)
//   stores: 0.125 instr/px (LDS-staged channel transpose, 512 B segments)
//           -> now NONTEMPORAL so the out stream doesn't evict xp from L3
//   flow:   0.03 instr/px
// ---------------------------------------------------------------------------
constexpr int GP_PX   = 128;            // pixels per 256-thread block
constexpr int RES_PAD = GP_PX + 5;      // 133: spreads bank stride on res[][]

__global__ __launch_bounds__(256) void gather_v3(
    const float* __restrict__ flow,
    const float* __restrict__ xp,
    float* __restrict__ out)
{
    __shared__ float prm[GP_PX][8];       // w00,w10,w01,w11, b00,b10,b01,b11  (4 KB)
    __shared__ float res[C][RES_PAD];     // staged output, px-major per channel (17 KB)

    // Bijective chunked XCD swizzle (nwg = 8192, divisible by 8).
    const int nwg = gridDim.x;
    const int nb  = (blockIdx.x & 7) * (nwg >> 3) + (blockIdx.x >> 3);
    const int pxbase = nb * GP_PX;
    const int t = threadIdx.x;

    // ---- Phase A: per-pixel coords/weights, coalesced flow loads ----------
    if (t < GP_PX) {
        const int p  = pxbase + t;
        const int w_ = p & (W - 1);
        const int h_ = p >> 10;

        const float fx = flow[p];
        const float fy = flow[HW + p];

        // Mirror reference arithmetic order exactly (fp32).
        const float gx = (fx + (float)w_) / (float)(W - 1) * 2.0f - 1.0f;
        const float gy = (fy + (float)h_) / (float)(H - 1) * 2.0f - 1.0f;
        const float ix = ((gx + 1.0f) * (float)W - 1.0f) * 0.5f;
        const float iy = ((gy + 1.0f) * (float)H - 1.0f) * 0.5f;

        const float x0f = floorf(ix);
        const float y0f = floorf(iy);
        const float wx1 = ix - x0f;
        const float wy1 = iy - y0f;
        const float wx0 = 1.0f - wx1;
        const float wy0 = 1.0f - wy1;

        const int x0 = (int)x0f;
        const int y0 = (int)y0f;
        const int x1 = x0 + 1;
        const int y1 = y0 + 1;

        const float vx0 = (x0 >= 0 && x0 < W) ? 1.0f : 0.0f;
        const float vx1 = (x1 >= 0 && x1 < W) ? 1.0f : 0.0f;
        const float vy0 = (y0 >= 0 && y0 < H) ? 1.0f : 0.0f;
        const float vy1 = (y1 >= 0 && y1 < H) ? 1.0f : 0.0f;

        const int xc0 = min(max(x0, 0), W - 1);
        const int xc1 = min(max(x1, 0), W - 1);
        const int yc0 = min(max(y0, 0), H - 1);
        const int yc1 = min(max(y1, 0), H - 1);

        prm[t][0] = wx0 * wy0 * vx0 * vy0;
        prm[t][1] = wx1 * wy0 * vx1 * vy0;
        prm[t][2] = wx0 * wy1 * vx0 * vy1;
        prm[t][3] = wx1 * wy1 * vx1 * vy1;
        prm[t][4] = __int_as_float((yc0 * W + xc0) * 8);
        prm[t][5] = __int_as_float((yc0 * W + xc1) * 8);
        prm[t][6] = __int_as_float((yc1 * W + xc0) * 8);
        prm[t][7] = __int_as_float((yc1 * W + xc1) * 8);
    }
    __syncthreads();

    // ---- Phase B: gather. 8 lanes per pixel (lane j owns channels 4j..4j+3),
    // each gather instr = 8 px x one full 128 B record. 4 px per thread. ----
    const int j  = t & 7;
    const int pl = t >> 3;              // 0..31
    const vf4* __restrict__ xq = (const vf4*)xp;

    float4 w4[4];
    int4   b4[4];
#pragma unroll
    for (int k = 0; k < 4; ++k) {
        const int px = k * 32 + pl;
        w4[k] = *(const float4*)&prm[px][0];
        const float4 bb = *(const float4*)&prm[px][4];
        b4[k].x = __float_as_int(bb.x) + j;
        b4[k].y = __float_as_int(bb.y) + j;
        b4[k].z = __float_as_int(bb.z) + j;
        b4[k].w = __float_as_int(bb.w) + j;
    }

    vf4 acc[4];
#pragma unroll
    for (int kk = 0; kk < 2; ++kk) {
        const int k0 = 2 * kk + 0;
        const int k1 = 2 * kk + 1;
        // 8 corner loads batched (8 x 16 B outstanding per lane).
        vf4 va0 = xq[b4[k0].x];
        vf4 vb0 = xq[b4[k0].y];
        vf4 vc0 = xq[b4[k0].z];
        vf4 vd0 = xq[b4[k0].w];
        vf4 va1 = xq[b4[k1].x];
        vf4 vb1 = xq[b4[k1].y];
        vf4 vc1 = xq[b4[k1].z];
        vf4 vd1 = xq[b4[k1].w];
        __builtin_amdgcn_sched_barrier(0);

        acc[k0].x = va0.x * w4[k0].x + vb0.x * w4[k0].y;
        acc[k0].y = va0.y * w4[k0].x + vb0.y * w4[k0].y;
        acc[k0].z = va0.z * w4[k0].x + vb0.z * w4[k0].y;
        acc[k0].w = va0.w * w4[k0].x + vb0.w * w4[k0].y;
        acc[k0].x += vc0.x * w4[k0].z + vd0.x * w4[k0].w;
        acc[k0].y += vc0.y * w4[k0].z + vd0.y * w4[k0].w;
        acc[k0].z += vc0.z * w4[k0].z + vd0.z * w4[k0].w;
        acc[k0].w += vc0.w * w4[k0].z + vd0.w * w4[k0].w;

        acc[k1].x = va1.x * w4[k1].x + vb1.x * w4[k1].y;
        acc[k1].y = va1.y * w4[k1].x + vb1.y * w4[k1].y;
        acc[k1].z = va1.z * w4[k1].x + vb1.z * w4[k1].y;
        acc[k1].w = va1.w * w4[k1].x + vb1.w * w4[k1].y;
        acc[k1].x += vc1.x * w4[k1].z + vd1.x * w4[k1].w;
        acc[k1].y += vc1.y * w4[k1].z + vd1.y * w4[k1].w;
        acc[k1].z += vc1.z * w4[k1].z + vd1.z * w4[k1].w;
        acc[k1].w += vc1.w * w4[k1].z + vd1.w * w4[k1].w;
    }

    // ---- Phase C: stage results to LDS (px-major per channel) -------------
#pragma unroll
    for (int k = 0; k < 4; ++k) {
        const int px = k * 32 + pl;
        res[4 * j + 0][px] = acc[k].x;
        res[4 * j + 1][px] = acc[k].y;
        res[4 * j + 2][px] = acc[k].z;
        res[4 * j + 3][px] = acc[k].w;
    }
    __syncthreads();

    // ---- Phase D: coalesced nontemporal float4 stores over channel planes -
    vf4* __restrict__ out4 = (vf4*)out;
    const int gbase = pxbase >> 2;
#pragma unroll
    for (int m = 0; m < 4; ++m) {
        const int f = m * 256 + t;
        const int c = f >> 5;          // channel
        const int g = f & 31;          // float4 group within 128-px tile
        vf4 o;
        o.x = res[c][4 * g + 0];
        o.y = res[c][4 * g + 1];
        o.z = res[c][4 * g + 2];
        o.w = res[c][4 * g + 3];
        __builtin_nontemporal_store(o, &out4[(size_t)c * (HW / 4) + gbase + g]);
    }
}

// ---------------------------------------------------------------------------
// Fallback (round-1 kernel) if workspace is too small for the transposed copy.
// ---------------------------------------------------------------------------
__global__ __launch_bounds__(256) void stn_warp_fallback(
    const float* __restrict__ flow,
    const float* __restrict__ x,
    float* __restrict__ out)
{
    const int tid = blockIdx.x * blockDim.x + threadIdx.x;
    if (tid >= HW) return;

    const int w = tid & (W - 1);
    const int h = tid >> 10;

    const float fx = flow[tid];
    const float fy = flow[HW + tid];

    const float gx = (fx + (float)w) / (float)(W - 1) * 2.0f - 1.0f;
    const float gy = (fy + (float)h) / (float)(H - 1) * 2.0f - 1.0f;
    const float ix = ((gx + 1.0f) * (float)W - 1.0f) * 0.5f;
    const float iy = ((gy + 1.0f) * (float)H - 1.0f) * 0.5f;

    const float x0f = floorf(ix);
    const float y0f = floorf(iy);
    const float wx1 = ix - x0f;
    const float wy1 = iy - y0f;
    const float wx0 = 1.0f - wx1;
    const float wy0 = 1.0f - wy1;

    const int x0 = (int)x0f;
    const int y0 = (int)y0f;
    const int x1 = x0 + 1;
    const int y1 = y0 + 1;

    const float vx0 = (x0 >= 0 && x0 < W) ? 1.0f : 0.0f;
    const float vx1 = (x1 >= 0 && x1 < W) ? 1.0f : 0.0f;
    const float vy0 = (y0 >= 0 && y0 < H) ? 1.0f : 0.0f;
    const float vy1 = (y1 >= 0 && y1 < H) ? 1.0f : 0.0f;

    const float w00 = wx0 * wy0 * vx0 * vy0;
    const float w10 = wx1 * wy0 * vx1 * vy0;
    const float w01 = wx0 * wy1 * vx0 * vy1;
    const float w11 = wx1 * wy1 * vx1 * vy1;

    const int xc0 = min(max(x0, 0), W - 1);
    const int xc1 = min(max(x1, 0), W - 1);
    const int yc0 = min(max(y0, 0), H - 1);
    const int yc1 = min(max(y1, 0), H - 1);

    const int o00 = yc0 * W + xc0;
    const int o10 = yc0 * W + xc1;
    const int o01 = yc1 * W + xc0;
    const int o11 = yc1 * W + xc1;

#pragma unroll
    for (int c = 0; c < C; ++c) {
        const float* __restrict__ xc = x + c * HW;
        const float v = xc[o00] * w00 + xc[o10] * w10
                      + xc[o01] * w01 + xc[o11] * w11;
        out[c * HW + tid] = v;
    }
}

extern "C" void kernel_launch(void* const* d_in, const int* in_sizes, int n_in,
                              void* d_out, int out_size, void* d_ws, size_t ws_size,
                              hipStream_t stream) {
    const float* flow = (const float*)d_in[0];  // [1,2,1024,1024]
    const float* x    = (const float*)d_in[1];  // [1,32,1024,1024]
    float* out        = (float*)d_out;          // [1,32,1024,1024]

    const size_t need = (size_t)HW * C * sizeof(float);  // 128 MB
    if (ws_size >= need) {
        float* xp = (float*)d_ws;
        transpose_v2<<<HW / TP_PX, 512, 0, stream>>>(x, xp);
        gather_v3<<<HW / GP_PX, 256, 0, stream>>>(flow, xp, out);
    } else {
        stn_warp_fallback<<<HW / 256, 256, 0, stream>>>(flow, x, out);
    }
}